// Round 8
// baseline (261.855 us; speedup 1.0000x reference)
//
#include <hip/hip_runtime.h>
#include <hip/hip_bf16.h>

// IcosahedronConv2d: out[b,v,o] = sum_{k,c} x[b, idx[v,k], c] * mask[v,k] * w[o,c,k] + bias[o]
// B=8, V=10242, C=128. v7: barrier-free main loop — each lane global-loads its exact
// MFMA A-fragment from the gathered row (no LDS staging, no per-slot barriers);
// masked slots -> zero-page via address select; batch->XCD swizzle; Os-transpose epilogue.

#define V_CNT    10242
#define CC       128
#define KS_ACT   7
#define BM       64
#define VT_PER_B 161         // ceil(10242/64)
#define BATCH    8

typedef short short8 __attribute__((ext_vector_type(8)));
typedef float f32x4  __attribute__((ext_vector_type(4)));

__device__ __forceinline__ unsigned f2bf(float f) {
    unsigned u = __float_as_uint(f);
    u += 0x7fffu + ((u >> 16) & 1u);      // RNE
    return u >> 16;
}

// ws layout (bytes):
//   xb : [0, 20975616)            8*10242*128 bf16  (row = 256 B)
//   wb : [20975616, 21204992)     7*128*128 bf16    Wb[k][o][c]
//   zp : [21204992, 21205504)     512 B zeros (zero-page for masked rows)
#define XB_OFF 0
#define WB_OFF 20975616
#define ZP_OFF 21204992

#define XB_BLOCKS 5121       // 8*10242*128/8 / 256
#define WB_BLOCKS 448        // 7*128*128 / 256

// fused prep: xb bf16 cast (8 elem/thread) + wb transform (1 elem/thread) + zero-page
__global__ void prep_kernel(const float* __restrict__ x, const float* __restrict__ w,
                            unsigned short* __restrict__ xb, unsigned short* __restrict__ wb,
                            unsigned short* __restrict__ zp, int n8) {
    int b = blockIdx.x;
    if (b < XB_BLOCKS) {
        int i = b * 256 + threadIdx.x;
        if (i < n8) {
            const float4* s = (const float4*)(x + (size_t)i * 8);
            float4 a = s[0], c = s[1];
            uint4 p;
            p.x = f2bf(a.x) | (f2bf(a.y) << 16);
            p.y = f2bf(a.z) | (f2bf(a.w) << 16);
            p.z = f2bf(c.x) | (f2bf(c.y) << 16);
            p.w = f2bf(c.z) | (f2bf(c.w) << 16);
            *(uint4*)(xb + (size_t)i * 8) = p;
        }
    } else if (b < XB_BLOCKS + WB_BLOCKS) {
        int i = (b - XB_BLOCKS) * 256 + threadIdx.x;   // < 114688
        int k = i >> 14;
        int r = i & 16383;
        int o = r >> 7;
        int c = r & 127;
        wb[i] = (unsigned short)f2bf(w[(o * CC + c) * 9 + k]);
    } else {
        if (threadIdx.x < 256) zp[threadIdx.x] = 0;    // 512 B zero-page
    }
}

__global__ __launch_bounds__(256, 3)
void icoconv_kernel(const char* __restrict__ wsb,      // d_ws base (xb at 0, zp at ZP_OFF)
                    const unsigned short* __restrict__ wb,
                    const float* __restrict__ bias,
                    const int* __restrict__ nidx,
                    const float* __restrict__ nmask,
                    float* __restrict__ out) {
    __shared__ __align__(16) float Os[64 * 132];       // epilogue transpose only (33792 B)

    const int tid  = threadIdx.x;
    const int lane = tid & 63;
    const int wid  = tid >> 6;            // 0..3 : 32-col o-strip
    // batch->XCD swizzle: XCD = dispatch % 8 = bb
    const int bb   = blockIdx.x & 7;
    const int vt   = blockIdx.x >> 3;     // 0..160
    const int vbase = vt * BM;

    const int l15 = lane & 15;
    const int khi = (lane >> 4) << 4;     // byte offset of this lane's k-group (16 B)

    // per-lane fragment offsets: off[mi][k] = byte offset into ws of the gathered row
    // for output row mi*16+l15, slot k (zero-page if masked), + lane k-group offset.
    const int bbV = bb * V_CNT;
    unsigned off[4][KS_ACT];
    #pragma unroll
    for (int mi = 0; mi < 4; ++mi) {
        int r = vbase + mi * 16 + l15;
        bool vv = r < V_CNT;
        #pragma unroll
        for (int k = 0; k < KS_ACT; ++k) {
            int g = 0; float mk = 0.f;
            if (vv) { g = nidx[r * 9 + k]; mk = nmask[r * 9 + k]; }
            unsigned o = (mk != 0.f) ? (unsigned)((bbV + g) * 256) : (unsigned)ZP_OFF;
            off[mi][k] = o + khi;
        }
    }

    f32x4 acc[4][2];
    #pragma unroll
    for (int i = 0; i < 4; ++i)
        #pragma unroll
        for (int j = 0; j < 2; ++j)
            acc[i][j] = f32x4{0.f, 0.f, 0.f, 0.f};

    // B lane base: Wb[k][o][c], o = wid*32 + ni*16 + l15, c-group = (lane>>4)*8
    const unsigned short* wlane = wb + (wid * 32 + l15) * CC + (khi >> 1);

    // main loop: straight-line, barrier-free; compiler pipelines loads across slots
    #pragma unroll
    for (int t = 0; t < KS_ACT; ++t) {
        const unsigned short* wks = wlane + t * (CC * CC);
        short8 bfr[4][2];
        #pragma unroll
        for (int kk = 0; kk < 4; ++kk)
            #pragma unroll
            for (int ni = 0; ni < 2; ++ni)
                bfr[kk][ni] = *(const short8*)(wks + ni * 16 * CC + kk * 32);

        #pragma unroll
        for (int kk = 0; kk < 4; ++kk) {
            short8 af[4];
            #pragma unroll
            for (int mi = 0; mi < 4; ++mi)
                af[mi] = *(const short8*)(wsb + off[mi][t] + kk * 64);
            #pragma unroll
            for (int mi = 0; mi < 4; ++mi)
                #pragma unroll
                for (int ni = 0; ni < 2; ++ni)
                    acc[mi][ni] = __builtin_amdgcn_mfma_f32_16x16x32_bf16(af[mi], bfr[kk][ni], acc[mi][ni], 0, 0, 0);
        }
    }

    // epilogue: acc -> Os (64x132 f32) -> coalesced nt float4 stores (one barrier total)
    #pragma unroll
    for (int mi = 0; mi < 4; ++mi) {
        int lrow = mi * 16 + ((lane >> 4) << 2);
        #pragma unroll
        for (int ni = 0; ni < 2; ++ni) {
            int lcol = wid * 32 + ni * 16 + l15;
            #pragma unroll
            for (int j = 0; j < 4; ++j)
                Os[(lrow + j) * 132 + lcol] = acc[mi][ni][j];
        }
    }
    __syncthreads();

    {
        const int r  = tid >> 2;          // 0..63
        const int cb = (tid & 3) << 5;    // 0,32,64,96
        const int vv = vbase + r;
        if (vv < V_CNT) {
            float* op = out + ((size_t)bb * V_CNT + vv) * CC + cb;
            #pragma unroll
            for (int q = 0; q < 8; ++q) {
                f32x4 val = *(const f32x4*)(Os + r * 132 + cb + q * 4);
                f32x4 bv  = *(const f32x4*)(bias + cb + q * 4);
                val = val + bv;
                __builtin_nontemporal_store(val, (f32x4*)(op + q * 4));
            }
        }
    }
}

extern "C" void kernel_launch(void* const* d_in, const int* in_sizes, int n_in,
                              void* d_out, int out_size, void* d_ws, size_t ws_size,
                              hipStream_t stream) {
    const float* x     = (const float*)d_in[0];
    const float* w     = (const float*)d_in[1];
    const float* bias  = (const float*)d_in[2];
    const int*   nidx  = (const int*)d_in[3];
    const float* nmask = (const float*)d_in[4];
    float* out = (float*)d_out;

    unsigned short* xb = (unsigned short*)((char*)d_ws + XB_OFF);
    unsigned short* wb = (unsigned short*)((char*)d_ws + WB_OFF);
    unsigned short* zp = (unsigned short*)((char*)d_ws + ZP_OFF);

    int n8 = BATCH * V_CNT * CC / 8;    // 1310976
    prep_kernel<<<XB_BLOCKS + WB_BLOCKS + 1, 256, 0, stream>>>(x, w, xb, wb, zp, n8);

    icoconv_kernel<<<BATCH * VT_PER_B, 256, 0, stream>>>((const char*)d_ws, wb, bias, nidx, nmask, out);
}